// Round 1
// baseline (915.899 us; speedup 1.0000x reference)
//
#include <hip/hip_runtime.h>

#define B_  8
#define C_  256
#define O_  256
#define H_  56
#define W_  56
#define HW_ 3136
#define KK_ 9
#define CK_ 2304   // C_*KK_

// ---------------------------------------------------------------------------
// Kernel 1: transpose w_dcn [O][C*KK] -> wT [C*KK][O] so A-tile staging in the
// main GEMM is coalesced. One-time 2.36 MB shuffle.
// ---------------------------------------------------------------------------
__global__ __launch_bounds__(256) void k_transpose(const float* __restrict__ w,
                                                   float* __restrict__ wT) {
    int i = blockIdx.x * 256 + threadIdx.x;   // i = ck*256 + o, exact 589824
    int o  = i & 255;
    int ck = i >> 8;
    wT[i] = w[o * CK_ + ck];
}

// ---------------------------------------------------------------------------
// Kernel 2: offset conv (3x3, pad 1, C=256 -> 18).
// Block = 512 threads = 64 positions x 8 c-groups. c-group is wave-uniform so
// w_off reads compile to scalar loads; 162 FMA per c-iter per thread.
// LDS reduction over the 8 c-groups, bias added at the end.
// ---------------------------------------------------------------------------
__global__ __launch_bounds__(512) void k_offconv(const float* __restrict__ x,
                                                 const float* __restrict__ w_off,
                                                 const float* __restrict__ b_off,
                                                 float* __restrict__ off) {
    __shared__ float partial[8][64][18];      // 36864 B
    int t  = threadIdx.x;
    int p  = t & 63;
    int cg = __builtin_amdgcn_readfirstlane(t >> 6);  // wave-uniform c-group
    int blk  = blockIdx.x;                    // 392 = 8 b * 49 tiles
    int b    = blk / 49;
    int pos0 = (blk % 49) * 64;
    int pos  = pos0 + p;
    int h = pos / W_;
    int w = pos % W_;
    const float* xb = x + (size_t)b * C_ * HW_;

    float acc[18];
#pragma unroll
    for (int i = 0; i < 18; ++i) acc[i] = 0.f;

    for (int cc = 0; cc < 32; ++cc) {
        int c = cg * 32 + cc;
        const float* xp = xb + c * HW_;
        float v[9];
#pragma unroll
        for (int dh = -1; dh <= 1; ++dh)
#pragma unroll
            for (int dw = -1; dw <= 1; ++dw) {
                int hh = h + dh, ww = w + dw;
                bool ok = (hh >= 0) & (hh < H_) & (ww >= 0) & (ww < W_);
                v[(dh + 1) * 3 + dw + 1] = ok ? xp[hh * W_ + ww] : 0.f;
            }
        const float* wc = w_off + c * KK_;
#pragma unroll
        for (int oc = 0; oc < 18; ++oc) {
            const float* wr = wc + oc * CK_;  // wave-uniform address -> s_load
#pragma unroll
            for (int k = 0; k < KK_; ++k)
                acc[oc] = fmaf(v[k], wr[k], acc[oc]);
        }
    }
#pragma unroll
    for (int oc = 0; oc < 18; ++oc) partial[cg][p][oc] = acc[oc];
    __syncthreads();

    for (int e = t; e < 64 * 18; e += 512) {  // e = oc*64 + p
        int oc = e >> 6;
        int pp = e & 63;
        float s = 0.f;
#pragma unroll
        for (int g = 0; g < 8; ++g) s += partial[g][pp][oc];
        s += b_off[oc];
        off[((size_t)b * 18 + oc) * HW_ + pos0 + pp] = s;
    }
}

// ---------------------------------------------------------------------------
// Kernel 3: deformable gather + implicit GEMM.
// Grid 784 = 392 spatial tiles (64 positions each) x 2 O-halves (128 each).
// Per block: build 9x64 bilinear (index,weight) tables in LDS ONCE (shared
// across all 256 channels), then K-loop over c: stage A (coalesced from wT)
// and B (4-pt gather from the 12.5 KB L1-resident channel plane) into LDS,
// 288 fp32 FMAs/thread/c. Thread owns 4 o x 8 n accumulators.
// ---------------------------------------------------------------------------
__global__ __launch_bounds__(256) void k_main(const float* __restrict__ x,
                                              const float* __restrict__ off,
                                              const float* __restrict__ wT,
                                              const float* __restrict__ b_dcn,
                                              float* __restrict__ out) {
    __shared__ int4   s_idx[KK_][64];     // 9216 B
    __shared__ float4 s_wgt[KK_][64];     // 9216 B
    __shared__ float  s_a[KK_ * 128];     // 4608 B  [k][oo]
    __shared__ float  s_bt[KK_ * 64];     // 2304 B  [k][n]

    int t    = threadIdx.x;
    int tile = blockIdx.x;
    int m    = tile & 1;
    int sp   = tile >> 1;                 // 0..391
    int b    = sp / 49;
    int pos0 = (sp % 49) * 64;
    int ob   = m * 128;

    // --- bilinear tables, once per block (amortized over 256 channels) ---
    for (int e = t; e < KK_ * 64; e += 256) {
        int k = e >> 6;
        int n = e & 63;
        int pos = pos0 + n;
        int h = pos / W_, w = pos % W_;
        float dy = off[((size_t)b * 18 + 2 * k) * HW_ + pos];
        float dx = off[((size_t)b * 18 + 2 * k + 1) * HW_ + pos];
        float py = (float)(h + k / 3 - 1) + dy;
        float px = (float)(w + k % 3 - 1) + dx;
        float y0f = floorf(py), x0f = floorf(px);
        float fy = py - y0f, fx = px - x0f;
        int y0 = (int)y0f, x0 = (int)x0f;
        int y1 = y0 + 1,   x1 = x0 + 1;
        float oy0 = (y0 >= 0 && y0 < H_) ? 1.f : 0.f;
        float oy1 = (y1 >= 0 && y1 < H_) ? 1.f : 0.f;
        float ox0 = (x0 >= 0 && x0 < W_) ? 1.f : 0.f;
        float ox1 = (x1 >= 0 && x1 < W_) ? 1.f : 0.f;
        int y0c = min(max(y0, 0), H_ - 1), y1c = min(max(y1, 0), H_ - 1);
        int x0c = min(max(x0, 0), W_ - 1), x1c = min(max(x1, 0), W_ - 1);
        s_idx[k][n] = make_int4(y0c * W_ + x0c, y0c * W_ + x1c,
                                y1c * W_ + x0c, y1c * W_ + x1c);
        s_wgt[k][n] = make_float4((1.f - fy) * (1.f - fx) * oy0 * ox0,
                                  (1.f - fy) * fx         * oy0 * ox1,
                                  fy         * (1.f - fx) * oy1 * ox0,
                                  fy         * fx         * oy1 * ox1);
    }

    int to = t & 31;                       // o = ob + to + 32*j  (bank-free)
    int tn = t >> 5;                       // n = tn*8 + i        (broadcast)
    float4 acc[4][2];
#pragma unroll
    for (int j = 0; j < 4; ++j) {
        acc[j][0] = make_float4(0.f, 0.f, 0.f, 0.f);
        acc[j][1] = make_float4(0.f, 0.f, 0.f, 0.f);
    }
    const float* xb = x + (size_t)b * C_ * HW_;
    __syncthreads();

    for (int c = 0; c < C_; ++c) {
        // stage A-tile: 9 x 128, coalesced from transposed weights
        for (int e = t; e < KK_ * 128; e += 256) {
            int r = e >> 7, oo = e & 127;
            s_a[e] = wT[(c * KK_ + r) * 256 + ob + oo];
        }
        // stage B-tile: 9 x 64 deformable samples of channel plane c
        const float* xp = xb + c * HW_;
        for (int e = t; e < KK_ * 64; e += 256) {
            int k = e >> 6, n = e & 63;
            int4   id = s_idx[k][n];
            float4 wg = s_wgt[k][n];
            s_bt[e] = wg.x * xp[id.x] + wg.y * xp[id.y] +
                      wg.z * xp[id.z] + wg.w * xp[id.w];
        }
        __syncthreads();
#pragma unroll
        for (int k = 0; k < KK_; ++k) {
            float4 b0 = *(const float4*)&s_bt[k * 64 + tn * 8];
            float4 b1 = *(const float4*)&s_bt[k * 64 + tn * 8 + 4];
#pragma unroll
            for (int j = 0; j < 4; ++j) {
                float a = s_a[k * 128 + to + 32 * j];
                acc[j][0].x = fmaf(a, b0.x, acc[j][0].x);
                acc[j][0].y = fmaf(a, b0.y, acc[j][0].y);
                acc[j][0].z = fmaf(a, b0.z, acc[j][0].z);
                acc[j][0].w = fmaf(a, b0.w, acc[j][0].w);
                acc[j][1].x = fmaf(a, b1.x, acc[j][1].x);
                acc[j][1].y = fmaf(a, b1.y, acc[j][1].y);
                acc[j][1].z = fmaf(a, b1.z, acc[j][1].z);
                acc[j][1].w = fmaf(a, b1.w, acc[j][1].w);
            }
        }
        __syncthreads();
    }

    // epilogue: bias + store (each thread writes two contiguous float4)
#pragma unroll
    for (int j = 0; j < 4; ++j) {
        int o = ob + to + 32 * j;
        float bias = b_dcn[o];
        float4 r0 = acc[j][0], r1 = acc[j][1];
        r0.x += bias; r0.y += bias; r0.z += bias; r0.w += bias;
        r1.x += bias; r1.y += bias; r1.z += bias; r1.w += bias;
        float* po = out + ((size_t)b * O_ + o) * HW_ + pos0 + tn * 8;
        *(float4*)po       = r0;
        *(float4*)(po + 4) = r1;
    }
}

extern "C" void kernel_launch(void* const* d_in, const int* in_sizes, int n_in,
                              void* d_out, int out_size, void* d_ws, size_t ws_size,
                              hipStream_t stream) {
    const float* x     = (const float*)d_in[0];
    const float* w_off = (const float*)d_in[1];
    const float* b_off = (const float*)d_in[2];
    const float* w_dcn = (const float*)d_in[3];
    const float* b_dcn = (const float*)d_in[4];
    float* out = (float*)d_out;

    // workspace layout (fully rewritten every launch; 0xAA poison is fine):
    //   off: 8*18*3136 = 451584 floats
    //   wT : 2304*256  = 589824 floats
    float* off = (float*)d_ws;
    float* wT  = off + 451584;

    k_transpose<<<2304, 256, 0, stream>>>(w_dcn, wT);
    k_offconv<<<392, 512, 0, stream>>>(x, w_off, b_off, off);
    k_main<<<784, 256, 0, stream>>>(x, off, wT, b_dcn, out);
}

// Round 2
// 524.796 us; speedup vs baseline: 1.7452x; 1.7452x over previous
//
#include <hip/hip_runtime.h>

#define B_  8
#define C_  256
#define O_  256
#define H_  56
#define W_  56
#define HW_ 3136
#define KK_ 9
#define CK_ 2304   // C_*KK_
#define NKC 72     // K-chunks of 32
#define APAD 40    // padded K-stride (bf16 elems) for LDS tiles: bank-conflict-free

typedef __bf16 bf16x8 __attribute__((ext_vector_type(8)));
typedef float  f32x4  __attribute__((ext_vector_type(4)));

// ---------------------------------------------------------------------------
// Kernel 1: build A = bf16(w_dcn) in tap-major K order, pre-padded to the
// exact LDS image: wA[kc][m=256][kl=40], kl<32 real (g = kc*32+kl,
// tap = g>>8, c = g&255), kl>=32 zero pad. A-staging in k_main becomes a
// verbatim contiguous copy. Total 737280 bf16 = 1.44 MB (L2-resident).
// ---------------------------------------------------------------------------
__global__ __launch_bounds__(256) void k_buildA(const float* __restrict__ w,
                                                __bf16* __restrict__ wA) {
    int i  = blockIdx.x * 256 + threadIdx.x;   // exact 2880*256
    int kc = i / (256 * APAD);
    int r  = i % (256 * APAD);
    int m  = r / APAD;
    int kl = r % APAD;
    float v = 0.f;
    if (kl < 32) {
        int g = kc * 32 + kl;
        int tap = g >> 8, c = g & 255;
        v = w[m * CK_ + c * KK_ + tap];
    }
    wA[i] = (__bf16)v;
}

// ---------------------------------------------------------------------------
// Kernel 2: offset conv (3x3, pad 1, C=256 -> 18). Unchanged from R1 (passed).
// ---------------------------------------------------------------------------
__global__ __launch_bounds__(512) void k_offconv(const float* __restrict__ x,
                                                 const float* __restrict__ w_off,
                                                 const float* __restrict__ b_off,
                                                 float* __restrict__ off) {
    __shared__ float partial[8][64][18];
    int t  = threadIdx.x;
    int p  = t & 63;
    int cg = __builtin_amdgcn_readfirstlane(t >> 6);
    int blk  = blockIdx.x;
    int b    = blk / 49;
    int pos0 = (blk % 49) * 64;
    int pos  = pos0 + p;
    int h = pos / W_;
    int w = pos % W_;
    const float* xb = x + (size_t)b * C_ * HW_;

    float acc[18];
#pragma unroll
    for (int i = 0; i < 18; ++i) acc[i] = 0.f;

    for (int cc = 0; cc < 32; ++cc) {
        int c = cg * 32 + cc;
        const float* xp = xb + c * HW_;
        float v[9];
#pragma unroll
        for (int dh = -1; dh <= 1; ++dh)
#pragma unroll
            for (int dw = -1; dw <= 1; ++dw) {
                int hh = h + dh, ww = w + dw;
                bool ok = (hh >= 0) & (hh < H_) & (ww >= 0) & (ww < W_);
                v[(dh + 1) * 3 + dw + 1] = ok ? xp[hh * W_ + ww] : 0.f;
            }
        const float* wc = w_off + c * KK_;
#pragma unroll
        for (int oc = 0; oc < 18; ++oc) {
            const float* wr = wc + oc * CK_;
#pragma unroll
            for (int k = 0; k < KK_; ++k)
                acc[oc] = fmaf(v[k], wr[k], acc[oc]);
        }
    }
#pragma unroll
    for (int oc = 0; oc < 18; ++oc) partial[cg][p][oc] = acc[oc];
    __syncthreads();

    for (int e = t; e < 64 * 18; e += 512) {
        int oc = e >> 6;
        int pp = e & 63;
        float s = 0.f;
#pragma unroll
        for (int g = 0; g < 8; ++g) s += partial[g][pp][oc];
        s += b_off[oc];
        off[((size_t)b * 18 + oc) * HW_ + pos0 + pp] = s;
    }
}

// ---------------------------------------------------------------------------
// Kernel 3: deformable gather + bf16 MFMA implicit GEMM.
// Grid 784 = 392 spatial tiles (64 pos) x 2 O-halves. Tile 128(O) x 64(n),
// K = 2304 in tap-major order, 72 chunks of 32.
// Per chunk: tap is wave-uniform; thread t gathers 8 channels for one n with
// a single shared idx4/wgt4; A-tile is a contiguous 10 KB copy from wA.
// 4 waves x (2 Mfrag x 4 Nfrag) mfma_f32_16x16x32_bf16; acc 32 VGPR/thread.
// LDS tiles stride APAD=40 bf16 (20 dwords): frag b128 reads conflict-free.
// ---------------------------------------------------------------------------
__global__ __launch_bounds__(256) void k_main(const float* __restrict__ x,
                                              const float* __restrict__ off,
                                              const __bf16* __restrict__ wA,
                                              const float* __restrict__ b_dcn,
                                              float* __restrict__ out) {
    __shared__ int4   s_idx[KK_][64];         //  9216 B
    __shared__ float4 s_wgt[KK_][64];         //  9216 B
    __shared__ __bf16 s_a[128 * APAD];        // 10240 B  [m][kl]
    __shared__ __bf16 s_b[64 * APAD];         //  5120 B  [n][kl]

    int t    = threadIdx.x;
    int tile = blockIdx.x;
    int mh   = tile & 1;
    int sp   = tile >> 1;
    int b    = sp / 49;
    int pos0 = (sp % 49) * 64;
    int ob   = mh * 128;

    // --- bilinear tables, once per block ---
    for (int e = t; e < KK_ * 64; e += 256) {
        int k = e >> 6;
        int n = e & 63;
        int pos = pos0 + n;
        int h = pos / W_, w = pos % W_;
        float dy = off[((size_t)b * 18 + 2 * k) * HW_ + pos];
        float dx = off[((size_t)b * 18 + 2 * k + 1) * HW_ + pos];
        float py = (float)(h + k / 3 - 1) + dy;
        float px = (float)(w + k % 3 - 1) + dx;
        float y0f = floorf(py), x0f = floorf(px);
        float fy = py - y0f, fx = px - x0f;
        int y0 = (int)y0f, x0 = (int)x0f;
        int y1 = y0 + 1,   x1 = x0 + 1;
        float oy0 = (y0 >= 0 && y0 < H_) ? 1.f : 0.f;
        float oy1 = (y1 >= 0 && y1 < H_) ? 1.f : 0.f;
        float ox0 = (x0 >= 0 && x0 < W_) ? 1.f : 0.f;
        float ox1 = (x1 >= 0 && x1 < W_) ? 1.f : 0.f;
        int y0c = min(max(y0, 0), H_ - 1), y1c = min(max(y1, 0), H_ - 1);
        int x0c = min(max(x0, 0), W_ - 1), x1c = min(max(x1, 0), W_ - 1);
        s_idx[k][n] = make_int4(y0c * W_ + x0c, y0c * W_ + x1c,
                                y1c * W_ + x0c, y1c * W_ + x1c);
        s_wgt[k][n] = make_float4((1.f - fy) * (1.f - fx) * oy0 * ox0,
                                  (1.f - fy) * fx         * oy0 * ox1,
                                  fy         * (1.f - fx) * oy1 * ox0,
                                  fy         * fx         * oy1 * ox1);
    }

    int lane = t & 63;
    int wv   = t >> 6;          // wave id 0..3
    int lid  = lane & 15;
    int quad = lane >> 4;

    f32x4 acc[2][4];
#pragma unroll
    for (int mi = 0; mi < 2; ++mi)
#pragma unroll
        for (int ni = 0; ni < 4; ++ni)
            acc[mi][ni] = (f32x4)(0.f);

    const float* xb = x + (size_t)b * C_ * HW_;
    __syncthreads();

    for (int kc = 0; kc < NKC; ++kc) {
        // --- A-tile: verbatim contiguous 10240 B copy (rows ob..ob+127) ---
        {
            const unsigned long long* src =
                (const unsigned long long*)(wA + (size_t)(kc * 256 + ob) * APAD);
            unsigned long long* dst = (unsigned long long*)s_a;
#pragma unroll
            for (int i = 0; i < 5; ++i) dst[t + i * 256] = src[t + i * 256];
        }
        // --- B-tile: thread gathers 8 channels for one n, one (uniform) tap ---
        {
            int tap = kc >> 3;             // 8 chunks per tap
            int c0  = (kc & 7) * 32;
            int n   = lane;
            int ko  = wv * 8;
            int4   id = s_idx[tap][n];
            float4 wg = s_wgt[tap][n];
            const float* p = xb + (size_t)(c0 + ko) * HW_;
            bf16x8 v8;
#pragma unroll
            for (int j = 0; j < 8; ++j) {
                float v = wg.x * p[id.x] + wg.y * p[id.y] +
                          wg.z * p[id.z] + wg.w * p[id.w];
                v8[j] = (__bf16)v;
                p += HW_;
            }
            *(bf16x8*)&s_b[n * APAD + ko] = v8;
        }
        __syncthreads();

        // --- fragments + MFMA ---
        const bf16x8* pa = (const bf16x8*)s_a;   // 16B units: m*5 + quad
        const bf16x8* pb = (const bf16x8*)s_b;
        bf16x8 af[2], bf[4];
#pragma unroll
        for (int mi = 0; mi < 2; ++mi)
            af[mi] = pa[(wv * 32 + mi * 16 + lid) * 5 + quad];
#pragma unroll
        for (int ni = 0; ni < 4; ++ni)
            bf[ni] = pb[(ni * 16 + lid) * 5 + quad];
#pragma unroll
        for (int mi = 0; mi < 2; ++mi)
#pragma unroll
            for (int ni = 0; ni < 4; ++ni)
                acc[mi][ni] = __builtin_amdgcn_mfma_f32_16x16x32_bf16(
                    af[mi], bf[ni], acc[mi][ni], 0, 0, 0);
        __syncthreads();
    }

    // --- epilogue: bias + store. D: col(n)=lane&15, row(m)=quad*4+reg ---
#pragma unroll
    for (int mi = 0; mi < 2; ++mi) {
#pragma unroll
        for (int r = 0; r < 4; ++r) {
            int m = wv * 32 + mi * 16 + quad * 4 + r;
            int o = ob + m;
            float bias = b_dcn[o];
            float* po = out + ((size_t)b * O_ + o) * HW_ + pos0 + lid;
#pragma unroll
            for (int ni = 0; ni < 4; ++ni)
                po[ni * 16] = acc[mi][ni][r] + bias;
        }
    }
}

extern "C" void kernel_launch(void* const* d_in, const int* in_sizes, int n_in,
                              void* d_out, int out_size, void* d_ws, size_t ws_size,
                              hipStream_t stream) {
    const float* x     = (const float*)d_in[0];
    const float* w_off = (const float*)d_in[1];
    const float* b_off = (const float*)d_in[2];
    const float* w_dcn = (const float*)d_in[3];
    const float* b_dcn = (const float*)d_in[4];
    float* out = (float*)d_out;

    // workspace: off = 451584 f32 (1.81 MB), wA = 737280 bf16 (1.47 MB)
    float*  off = (float*)d_ws;
    __bf16* wA  = (__bf16*)(off + 451584);

    k_buildA <<<2880, 256, 0, stream>>>(w_dcn, wA);
    k_offconv<<<392, 512, 0, stream>>>(x, w_off, b_off, off);
    k_main   <<<784, 256, 0, stream>>>(x, off, wA, b_dcn, out);
}

// Round 3
// 340.531 us; speedup vs baseline: 2.6896x; 1.5411x over previous
//
#include <hip/hip_runtime.h>

#define B_  8
#define C_  256
#define O_  256
#define H_  56
#define W_  56
#define HW_ 3136
#define KK_ 9
#define CK_ 2304   // C_*KK_
#define NKC 72     // K-chunks of 32

typedef __bf16 bf16x8 __attribute__((ext_vector_type(8)));
typedef float  f32x4  __attribute__((ext_vector_type(4)));

// async 16B/lane global->LDS: lds base must be wave-uniform; HW adds lane*16.
__device__ __forceinline__ void async16(const void* gsrc_lane, void* lds_uniform) {
    __builtin_amdgcn_global_load_lds(
        (const __attribute__((address_space(1))) unsigned int*)gsrc_lane,
        (__attribute__((address_space(3))) unsigned int*)lds_uniform, 16, 0, 0);
}

// ---------------------------------------------------------------------------
// Kernel 1: A = bf16(w_dcn), tap-major K, unpadded LDS image:
// wA[kc][m=256][kl=32], g=kc*32+kl, tap=g>>8, c=g&255. 1.18 MB, L2-resident.
// ---------------------------------------------------------------------------
__global__ __launch_bounds__(256) void k_buildA(const float* __restrict__ w,
                                                __bf16* __restrict__ wA) {
    int i  = blockIdx.x * 256 + threadIdx.x;   // exact 2304*256 = 589824
    int kc = i >> 13;          // /8192
    int r  = i & 8191;
    int m  = r >> 5;
    int kl = r & 31;
    int gk = kc * 32 + kl;
    int tap = gk >> 8, c = gk & 255;
    wA[i] = (__bf16)w[m * CK_ + c * KK_ + tap];
}

// ---------------------------------------------------------------------------
// Kernel 2: offset conv (3x3, pad 1, C=256 -> 18). Unchanged (passed R1/R2).
// ---------------------------------------------------------------------------
__global__ __launch_bounds__(512) void k_offconv(const float* __restrict__ x,
                                                 const float* __restrict__ w_off,
                                                 const float* __restrict__ b_off,
                                                 float* __restrict__ off) {
    __shared__ float partial[8][64][18];
    int t  = threadIdx.x;
    int p  = t & 63;
    int cg = __builtin_amdgcn_readfirstlane(t >> 6);
    int blk  = blockIdx.x;
    int b    = blk / 49;
    int pos0 = (blk % 49) * 64;
    int pos  = pos0 + p;
    int h = pos / W_;
    int w = pos % W_;
    const float* xb = x + (size_t)b * C_ * HW_;

    float acc[18];
#pragma unroll
    for (int i = 0; i < 18; ++i) acc[i] = 0.f;

    for (int cc = 0; cc < 32; ++cc) {
        int c = cg * 32 + cc;
        const float* xp = xb + c * HW_;
        float v[9];
#pragma unroll
        for (int dh = -1; dh <= 1; ++dh)
#pragma unroll
            for (int dw = -1; dw <= 1; ++dw) {
                int hh = h + dh, ww = w + dw;
                bool ok = (hh >= 0) & (hh < H_) & (ww >= 0) & (ww < W_);
                v[(dh + 1) * 3 + dw + 1] = ok ? xp[hh * W_ + ww] : 0.f;
            }
        const float* wc = w_off + c * KK_;
#pragma unroll
        for (int oc = 0; oc < 18; ++oc) {
            const float* wr = wc + oc * CK_;
#pragma unroll
            for (int k = 0; k < KK_; ++k)
                acc[oc] = fmaf(v[k], wr[k], acc[oc]);
        }
    }
#pragma unroll
    for (int oc = 0; oc < 18; ++oc) partial[cg][p][oc] = acc[oc];
    __syncthreads();

    for (int e = t; e < 64 * 18; e += 512) {
        int oc = e >> 6;
        int pp = e & 63;
        float s = 0.f;
#pragma unroll
        for (int g = 0; g < 8; ++g) s += partial[g][pp][oc];
        s += b_off[oc];
        off[((size_t)b * 18 + oc) * HW_ + pos0 + pp] = s;
    }
}

// ---------------------------------------------------------------------------
// Kernel 3: gather -> materialize V[u][kc][n=64][kl=32] bf16 (the exact GEMM
// B-tile image). Block = (unit u, c-slice s of 64 channels), 256 threads.
// Thread = (n, 8 channels). Tap-INNERMOST: the wave's 8 channel-plane windows
// stay L1-resident across all 9 taps. No barriers in the loop -> full MLP.
// ---------------------------------------------------------------------------
__global__ __launch_bounds__(256) void k_gather(const float* __restrict__ x,
                                                const float* __restrict__ off,
                                                __bf16* __restrict__ V,
                                                int unit0) {
    __shared__ int4   s_idx[KK_][64];
    __shared__ float4 s_wgt[KK_][64];
    int t = threadIdx.x;
    int u = blockIdx.x >> 2;      // local unit
    int s = blockIdx.x & 3;       // c-slice (2 c-groups of 32)
    int g = unit0 + u;
    int b = g / 49;
    int pos0 = (g % 49) * 64;

    for (int e = t; e < KK_ * 64; e += 256) {
        int k = e >> 6;
        int n = e & 63;
        int pos = pos0 + n;
        int h = pos / W_, w = pos % W_;
        float dy = off[((size_t)b * 18 + 2 * k) * HW_ + pos];
        float dx = off[((size_t)b * 18 + 2 * k + 1) * HW_ + pos];
        float py = (float)(h + k / 3 - 1) + dy;
        float px = (float)(w + k % 3 - 1) + dx;
        float y0f = floorf(py), x0f = floorf(px);
        float fy = py - y0f, fx = px - x0f;
        int y0 = (int)y0f, x0 = (int)x0f;
        int y1 = y0 + 1,   x1 = x0 + 1;
        float oy0 = (y0 >= 0 && y0 < H_) ? 1.f : 0.f;
        float oy1 = (y1 >= 0 && y1 < H_) ? 1.f : 0.f;
        float ox0 = (x0 >= 0 && x0 < W_) ? 1.f : 0.f;
        float ox1 = (x1 >= 0 && x1 < W_) ? 1.f : 0.f;
        int y0c = min(max(y0, 0), H_ - 1), y1c = min(max(y1, 0), H_ - 1);
        int x0c = min(max(x0, 0), W_ - 1), x1c = min(max(x1, 0), W_ - 1);
        s_idx[k][n] = make_int4(y0c * W_ + x0c, y0c * W_ + x1c,
                                y1c * W_ + x0c, y1c * W_ + x1c);
        s_wgt[k][n] = make_float4((1.f - fy) * (1.f - fx) * oy0 * ox0,
                                  (1.f - fy) * fx         * oy0 * ox1,
                                  fy         * (1.f - fx) * oy1 * ox0,
                                  fy         * fx         * oy1 * ox1);
    }
    __syncthreads();

    int n  = t & 63;
    int cg = t >> 6;
    const float* xb = x + (size_t)b * C_ * HW_;
    char* Vu = (char*)V + (size_t)u * NKC * 4096;

#pragma unroll
    for (int cg2 = 0; cg2 < 2; ++cg2) {
        int cs = s * 2 + cg2;                  // c-group 0..7
        const float* pc = xb + (size_t)(cs * 32 + cg * 8) * HW_;
#pragma unroll
        for (int tap = 0; tap < KK_; ++tap) {
            int kc = tap * 8 + cs;
            int4   id = s_idx[tap][n];
            float4 wg = s_wgt[tap][n];
            const float* p = pc;
            bf16x8 v8;
#pragma unroll
            for (int j = 0; j < 8; ++j) {
                float v = wg.x * p[id.x] + wg.y * p[id.y] +
                          wg.z * p[id.z] + wg.w * p[id.w];
                v8[j] = (__bf16)v;
                p += HW_;
            }
            *(bf16x8*)(Vu + (size_t)kc * 4096 + n * 64 + cg * 16) = v8;
        }
    }
}

// ---------------------------------------------------------------------------
// Kernel 4: clean bf16 MFMA GEMM. Tile 128(O) x 64(n), K=2304 (72 chunks).
// A and B staged with verbatim contiguous global_load_lds(16B) - no VGPR
// round-trip, no scattered loads inside the barriers. O-half pairs mapped to
// the SAME XCD (u=(x>>4)*8+(x&7), mh=(x>>3)&1) so V is L2-hit on 2nd read.
// ---------------------------------------------------------------------------
__global__ __launch_bounds__(256) void k_gemm(const __bf16* __restrict__ V,
                                              const __bf16* __restrict__ wA,
                                              const float* __restrict__ b_dcn,
                                              float* __restrict__ out,
                                              int unit0, int upc) {
    __shared__ __bf16 s_a[128 * 32];   // 8192 B
    __shared__ __bf16 s_b[64 * 32];    // 4096 B

    int xk = blockIdx.x;
    int u  = (xk >> 4) * 8 + (xk & 7);
    int mh = (xk >> 3) & 1;
    if (u >= upc) return;
    int g    = unit0 + u;
    int b    = g / 49;
    int pos0 = (g % 49) * 64;
    int ob   = mh * 128;

    int t    = threadIdx.x;
    int lane = t & 63;
    int wv   = t >> 6;
    int lid  = lane & 15;
    int quad = lane >> 4;

    f32x4 acc[2][4];
#pragma unroll
    for (int mi = 0; mi < 2; ++mi)
#pragma unroll
        for (int ni = 0; ni < 4; ++ni)
            acc[mi][ni] = (f32x4)(0.f);

    const char* gA0 = (const char*)(wA + (size_t)ob * 32);
    const char* gB0 = (const char*)(V + (size_t)u * NKC * 2048);
    int lo = lane * 16;

    for (int kc = 0; kc < NKC; ++kc) {
        const char* ga = gA0 + (size_t)kc * 16384;  // 256*32*2 B per kc
        const char* gb = gB0 + (size_t)kc * 4096;
        // A: 8192 B = 4 waves x 2 calls x 1024 B; B: 4096 B = 4 waves x 1 call
        async16(ga + wv * 1024 + lo,        (char*)s_a + wv * 1024);
        async16(ga + 4096 + wv * 1024 + lo, (char*)s_a + 4096 + wv * 1024);
        async16(gb + wv * 1024 + lo,        (char*)s_b + wv * 1024);
        __syncthreads();

        const bf16x8* pa = (const bf16x8*)s_a;   // row = 4 x 16B chunks
        const bf16x8* pb = (const bf16x8*)s_b;
        bf16x8 af[2], bf[4];
#pragma unroll
        for (int mi = 0; mi < 2; ++mi)
            af[mi] = pa[(wv * 32 + mi * 16 + lid) * 4 + quad];
#pragma unroll
        for (int ni = 0; ni < 4; ++ni)
            bf[ni] = pb[(ni * 16 + lid) * 4 + quad];
#pragma unroll
        for (int mi = 0; mi < 2; ++mi)
#pragma unroll
            for (int ni = 0; ni < 4; ++ni)
                acc[mi][ni] = __builtin_amdgcn_mfma_f32_16x16x32_bf16(
                    af[mi], bf[ni], acc[mi][ni], 0, 0, 0);
        __syncthreads();
    }

    // epilogue: bias + store. D: col(n)=lane&15, row(m)=quad*4+reg
#pragma unroll
    for (int mi = 0; mi < 2; ++mi) {
#pragma unroll
        for (int r = 0; r < 4; ++r) {
            int m = wv * 32 + mi * 16 + quad * 4 + r;
            int o = ob + m;
            float bias = b_dcn[o];
            float* po = out + ((size_t)b * O_ + o) * HW_ + pos0 + lid;
#pragma unroll
            for (int ni = 0; ni < 4; ++ni)
                po[ni * 16] = acc[mi][ni][r] + bias;
        }
    }
}

extern "C" void kernel_launch(void* const* d_in, const int* in_sizes, int n_in,
                              void* d_out, int out_size, void* d_ws, size_t ws_size,
                              hipStream_t stream) {
    const float* x     = (const float*)d_in[0];
    const float* w_off = (const float*)d_in[1];
    const float* b_off = (const float*)d_in[2];
    const float* w_dcn = (const float*)d_in[3];
    const float* b_dcn = (const float*)d_in[4];
    float* out = (float*)d_out;

    // workspace: off 1.81 MB | wA 1.18 MB | V (chunked, 0.295 MB per unit)
    const size_t offBytes = (size_t)451584 * 4;
    const size_t wABytes  = (size_t)589824 * 2;
    const size_t unitB    = (size_t)NKC * 64 * 32 * 2;   // 294912
    float*  off = (float*)d_ws;
    __bf16* wA  = (__bf16*)((char*)d_ws + offBytes);
    __bf16* V   = (__bf16*)((char*)d_ws + offBytes + wABytes);

    size_t avail = ws_size > offBytes + wABytes ? ws_size - offBytes - wABytes : 0;
    int upc = (int)(avail / unitB);
    if (upc > 392) upc = 392;
    if (upc < 1)  upc = 1;   // ws too small would corrupt; assume >= ~4 MB

    k_buildA <<<2304, 256, 0, stream>>>(w_dcn, wA);
    k_offconv<<<392, 512, 0, stream>>>(x, w_off, b_off, off);
    for (int u0 = 0; u0 < 392; u0 += upc) {
        int n = 392 - u0 < upc ? 392 - u0 : upc;
        k_gather<<<n * 4, 256, 0, stream>>>(x, off, V, u0);
        k_gemm  <<<((n + 7) / 8) * 16, 256, 0, stream>>>(V, wA, b_dcn, out, u0, n);
    }
}